// Round 3
// baseline (440.753 us; speedup 1.0000x reference)
//
#include <hip/hip_runtime.h>
#include <hip/hip_bf16.h>
#include <stdint.h>

// ---------------------------------------------------------------- geometry
#define E_DIM 512
#define GNB   35        // basis functions per input feature (G + K_DEG)
#define KSP   17920     // 512*35 spline K
#define KAUG  18432     // spline + base (512)
#define MTOK  2048      // B*L
#define BKW   128       // K window (cols per LDS tile)
#define NWIN  144       // KAUG/BKW
#define WINB  140       // first base-branch window (17920/128, exact)
#define BM    128
#define BN    128

typedef __attribute__((ext_vector_type(8))) short  short8;   // 8 bf16 (4 VGPR) MFMA A/B frag
typedef __attribute__((ext_vector_type(4))) short  short4v;
typedef __attribute__((ext_vector_type(4))) float  floatx4;  // MFMA C/D frag + indexable float4

__device__ __forceinline__ short f2bf(float f) {
  __hip_bfloat16 h = __float2bfloat16(f);
  return *reinterpret_cast<short*>(&h);
}
__device__ __forceinline__ float silu_f(float x) { return x / (1.0f + __expf(-x)); }

__device__ __forceinline__ void gload_lds16(const void* g, void* l) {
  typedef const __attribute__((address_space(1))) void* gp_t;
  typedef __attribute__((address_space(3))) void* lp_t;
  __builtin_amdgcn_global_load_lds((gp_t)g, (lp_t)l, 16, 0, 0);
}

// slice-major LDS tiling: tile[16 slices][128 rows][16B]; slice sl holds
// k-range kofs(sl)..kofs(sl)+7 where k = kc*32 + kg*8 + j  (sl = kc*4+kg).
__device__ __forceinline__ int kofs(int sl) { return ((sl >> 2) << 5) + ((sl & 3) << 3); }

// ---------------------------------------------------------------------------
// wconv (FULL path only): [KAUG x 512] f32 (w_sp rows k=e*35+g, w_base rows
// k=17920+e) -> bf16 waugT[3][512][KAUG] (o-major, k contiguous, LINEAR).
// KSP = 280*64 so each 64-row tile comes from exactly one source.
// ---------------------------------------------------------------------------
__global__ __launch_bounds__(256) void wconv_kernel(
    const float* __restrict__ wq_sp, const float* __restrict__ wq_base,
    const float* __restrict__ wk_sp, const float* __restrict__ wk_base,
    const float* __restrict__ wv_sp, const float* __restrict__ wv_base,
    __hip_bfloat16* __restrict__ waugT)
{
  __shared__ float tile[64][65];  // +1 pad
  const int tz = blockIdx.z;
  const float* wsp = tz == 0 ? wq_sp : (tz == 1 ? wk_sp : wv_sp);
  const float* wb  = tz == 0 ? wq_base : (tz == 1 ? wk_base : wv_base);
  const int k0 = blockIdx.x * 64;
  const int o0 = blockIdx.y * 64;
  const int t  = threadIdx.x;
  const float* srcb = (k0 < KSP) ? wsp + (size_t)k0 * E_DIM
                                 : wb + (size_t)(k0 - KSP) * E_DIM;
#pragma unroll
  for (int it = 0; it < 4; ++it) {
    int idx = it * 256 + t;
    int r = idx >> 4, c4 = (idx & 15) * 4;
    floatx4 v = *(const floatx4*)&srcb[(size_t)r * E_DIM + o0 + c4];
    tile[r][c4] = v.x; tile[r][c4 + 1] = v.y;
    tile[r][c4 + 2] = v.z; tile[r][c4 + 3] = v.w;
  }
  __syncthreads();
  __hip_bfloat16* dst = waugT + (size_t)tz * E_DIM * KAUG;
#pragma unroll
  for (int it = 0; it < 4; ++it) {
    int idx = it * 256 + t;
    int ro = idx >> 4, kc = (idx & 15) * 4;
    short4v s;
    s.x = f2bf(tile[kc][ro]);     s.y = f2bf(tile[kc + 1][ro]);
    s.z = f2bf(tile[kc + 2][ro]); s.w = f2bf(tile[kc + 3][ro]);
    *(short4v*)&dst[(size_t)(o0 + ro) * KAUG + k0 + kc] = s;   // 8B store
  }
}

// ---------------------------------------------------------------------------
// Fused KAN GEMM: C[tz] = [basis(X) | silu(X)] @ W_aug.  A built in LDS.
// 1-D grid 768 blocks; XCD-chunk swizzle so all 16 m-tiles of one B panel
// land on one XCD (L2 panel reuse).  LDS tiles are slice-major (bank-clean).
// ---------------------------------------------------------------------------
template<int MODE>
__global__ __launch_bounds__(256) void kan_gemm(
    const float* __restrict__ q, const float* __restrict__ k_in,
    const float* __restrict__ v, const __hip_bfloat16* __restrict__ waugT,
    const float* __restrict__ wq_sp, const float* __restrict__ wq_base,
    const float* __restrict__ wk_sp, const float* __restrict__ wk_base,
    const float* __restrict__ wv_sp, const float* __restrict__ wv_base,
    float* __restrict__ C)
{
  __shared__ char pA[32768];   // [16][128][16B]
  __shared__ char pB[32768];   // [16][128][16B]

  // T1: bijective XCD chunking (768 = 8 * 96)
  const int bid = blockIdx.x;
  const int lid = (bid & 7) * 96 + (bid >> 3);
  const int mx = lid & 15;            // m-tile (fastest -> same panel, same XCD)
  const int ny = (lid >> 4) & 3;      // n-tile
  const int z  = lid >> 6;            // 0..11 = tz*4 + ks
  const int tz = z >> 2;
  const int ks = z & 3;

  const float* X = tz == 0 ? q : (tz == 1 ? k_in : v);
  const float* Wsp = tz == 0 ? wq_sp : (tz == 1 ? wk_sp : wv_sp);
  const float* Wb  = tz == 0 ? wq_base : (tz == 1 ? wk_base : wv_base);
  const char* WTb = (const char*)(waugT + (size_t)tz * E_DIM * KAUG);
  float* Cout = C + (size_t)tz * MTOK * E_DIM;

  const int m0 = mx * BM;
  const int n0 = ny * BN;
  const int t = threadIdx.x;
  const int lane = t & 63, wid = t >> 6;
  const int wm = wid >> 1, wn = wid & 1;    // 2x2 waves of 64x64
  const int fr = lane & 15, kg = lane >> 4;

  floatx4 acc[4][4];
  const floatx4 zf = {0.f, 0.f, 0.f, 0.f};
#pragma unroll
  for (int i = 0; i < 4; ++i)
#pragma unroll
    for (int j = 0; j < 4; ++j) acc[i][j] = zf;

  const int colt = t & 127;           // B staging: col for this thread
  const int slhi = t >> 7;            // 0/1

  const int w_lo = ks * (NWIN / 4), w_hi = w_lo + (NWIN / 4);
  for (int win = w_lo; win < w_hi; ++win) {
    const int k0 = win * BKW;
    const bool spline = (win < WINB);
    __syncthreads();   // previous window's frag reads complete

    // ---- issue B stage (async, stays in flight through A build)
    if (MODE == 0) {
#pragma unroll
      for (int p = 0; p < 8; ++p) {
        const int sl = 2 * p + slhi;
        size_t goff = ((size_t)(n0 + colt) * KAUG + k0 + kofs(sl)) * 2;
        gload_lds16(WTb + goff, pB + p * 4096 + t * 16);
      }
    } else {
      // f32 weights, reg transpose, slice-major writes
      const float* Wrow = spline ? Wsp : Wb;
      const int koff0 = spline ? k0 : k0 - KSP;
      const int g  = t & 31;
      const int rg = t >> 5;
#pragma unroll
      for (int p = 0; p < 4; ++p) {
        const int r0 = (p * 8 + rg) * 4;      // k-local, step 4
        const int sl = ((r0 >> 5) << 2) | ((r0 >> 3) & 3);
        float rv[4][4];
#pragma unroll
        for (int j = 0; j < 4; ++j) {
          const float* src = &Wrow[(size_t)(koff0 + r0 + j) * E_DIM + n0 + g];
#pragma unroll
          for (int j2 = 0; j2 < 4; ++j2) rv[j][j2] = src[32 * j2];
        }
#pragma unroll
        for (int j2 = 0; j2 < 4; ++j2) {
          const int nloc = g + 32 * j2;
          short4v sv;
          sv.x = f2bf(rv[0][j2]); sv.y = f2bf(rv[1][j2]);
          sv.z = f2bf(rv[2][j2]); sv.w = f2bf(rv[3][j2]);
          *(short4v*)&pB[sl * 2048 + nloc * 16 + (r0 & 7) * 2] = sv;
        }
      }
    }

    // ---- build A tile
    if (spline) {
      const int4 z4 = make_int4(0, 0, 0, 0);
#pragma unroll
      for (int p = 0; p < 8; ++p) ((int4*)pA)[p * 256 + t] = z4;
      // zeros visible before scatter; do NOT drain vmcnt (B still in flight)
      asm volatile("s_waitcnt lgkmcnt(0)" ::: "memory");
      __builtin_amdgcn_s_barrier();
      const int elo = k0 / GNB;
      int ehi = (k0 + BKW - 1) / GNB; if (ehi > 511) ehi = 511;
      const int ne = ehi - elo + 1;            // 4 or 5
      const int npairs = BM * ne;
      for (int p = t; p < npairs; p += 256) {
        int m, ei;
        if (ne == 4) { m = p >> 2; ei = p & 3; }
        else         { m = (p * 52429) >> 18; ei = p - m * 5; }
        const int e = elo + ei;
        float x = X[(size_t)(m0 + m) * E_DIM + e];
        x = fminf(fmaxf(x, -3.0f), 3.0f - 1e-4f);
        float u = (x + 3.0f) * (16.0f / 3.0f);
        int ii = (int)u; ii = ii > 31 ? 31 : ii;
        float tt = u - (float)ii;
        float omt = 1.0f - tt;
        float t2 = tt * tt, t3 = t2 * tt;
        float w4[4];
        w4[0] = omt * omt * omt * (1.0f / 6.0f);
        w4[1] = (3.0f * t3 - 6.0f * t2 + 4.0f) * (1.0f / 6.0f);
        w4[2] = (-3.0f * t3 + 3.0f * t2 + 3.0f * tt + 1.0f) * (1.0f / 6.0f);
        w4[3] = t3 * (1.0f / 6.0f);
        const int c = e * GNB + ii - k0;
#pragma unroll
        for (int j = 0; j < 4; ++j) {
          const int k = c + j;
          if (k >= 0 && k < BKW) {
            const int sl = ((k >> 5) << 2) | ((k >> 3) & 3);
            *(short*)&pA[sl * 2048 + m * 16 + (k & 7) * 2] = f2bf(w4[j]);
          }
        }
      }
    } else {
      // base window: A = silu(x); conflict-free slice-major writes
      const int e0 = k0 - KSP;
#pragma unroll
      for (int p = 0; p < 8; ++p) {
        const int id = p * 256 + t;
        const int m = id & 127, sl = id >> 7;
        const float* xs = &X[(size_t)(m0 + m) * E_DIM + e0 + kofs(sl)];
        floatx4 a = *(const floatx4*)xs;
        floatx4 b = *(const floatx4*)(xs + 4);
        short8 pk;
        pk[0] = f2bf(silu_f(a.x)); pk[1] = f2bf(silu_f(a.y));
        pk[2] = f2bf(silu_f(a.z)); pk[3] = f2bf(silu_f(a.w));
        pk[4] = f2bf(silu_f(b.x)); pk[5] = f2bf(silu_f(b.y));
        pk[6] = f2bf(silu_f(b.z)); pk[7] = f2bf(silu_f(b.w));
        *(short8*)&pA[sl * 2048 + m * 16] = pk;
      }
    }
    // A writes (lgkm) + B gloads (vm) must complete before frag reads
    asm volatile("s_waitcnt vmcnt(0) lgkmcnt(0)" ::: "memory");
    __builtin_amdgcn_s_barrier();

    // ---- MFMA: 4 k-chunks x 16 frags (slice-major, conflict-free reads)
    const int arow = (wm * 64 + fr) * 16;
    const int brow = (wn * 64 + fr) * 16;
    const int sbase = kg * 2048;
#pragma unroll
    for (int kc = 0; kc < 4; ++kc) {
      const int so = sbase + kc * 8192;
      short8 af[4], bfv[4];
#pragma unroll
      for (int fm = 0; fm < 4; ++fm)
        af[fm] = *(const short8*)&pA[so + arow + fm * 256];
#pragma unroll
      for (int fn = 0; fn < 4; ++fn)
        bfv[fn] = *(const short8*)&pB[so + brow + fn * 256];
#pragma unroll
      for (int fm = 0; fm < 4; ++fm)
#pragma unroll
        for (int fn = 0; fn < 4; ++fn)
          acc[fm][fn] = __builtin_amdgcn_mfma_f32_16x16x32_bf16(
              af[fm], bfv[fn], acc[fm][fn], 0, 0, 0);
    }
  }

  // ---- split-K epilogue
  const int rowb = kg * 4;
#pragma unroll
  for (int fm = 0; fm < 4; ++fm)
#pragma unroll
    for (int fn = 0; fn < 4; ++fn)
#pragma unroll
      for (int r = 0; r < 4; ++r)
        atomicAdd(&Cout[(size_t)(m0 + wm * 64 + fm * 16 + rowb + r) * E_DIM
                        + (n0 + wn * 64 + fn * 16 + fr)],
                  acc[fm][fn][r]);
}

// ---------------------------------------------------------------------------
// KtV[b,h,d,e] = sum_s K[b,h,s,d] * V[b,h,s,e]   (f32, s-chunked + atomics)
// ---------------------------------------------------------------------------
__global__ __launch_bounds__(256) void ktv_kernel(const float* __restrict__ C,
                                                  float* __restrict__ KtV)
{
  __shared__ float Ks[64][64];
  __shared__ float Vs[64][64];
  const int sc = blockIdx.x, bh = blockIdx.y;
  const int b = bh >> 3, h = bh & 7;
  const int t = threadIdx.x;
  const size_t base = ((size_t)(b * 1024 + sc * 64)) * E_DIM + h * 64;
  const float* Kp = C + (size_t)MTOK * E_DIM + base;
  const float* Vp = C + (size_t)2 * MTOK * E_DIM + base;
#pragma unroll
  for (int p = 0; p < 16; ++p) {
    int idx = p * 256 + t;
    int r = idx >> 6, c = idx & 63;
    Ks[r][c] = Kp[(size_t)r * E_DIM + c];
    Vs[r][c] = Vp[(size_t)r * E_DIM + c];
  }
  __syncthreads();
  const int d0 = (t & 15) * 4, e0 = (t >> 4) * 4;
  float acc[4][4] = {};
  for (int s = 0; s < 64; ++s) {
    float4 kv = *(const float4*)&Ks[s][d0];
    float4 vv = *(const float4*)&Vs[s][e0];
    float ka[4] = {kv.x, kv.y, kv.z, kv.w};
    float va[4] = {vv.x, vv.y, vv.z, vv.w};
#pragma unroll
    for (int i = 0; i < 4; ++i)
#pragma unroll
      for (int j = 0; j < 4; ++j) acc[i][j] = __fmaf_rn(ka[i], va[j], acc[i][j]);
  }
  float* dst = KtV + (size_t)bh * 4096;
#pragma unroll
  for (int i = 0; i < 4; ++i)
#pragma unroll
    for (int j = 0; j < 4; ++j)
      atomicAdd(&dst[(d0 + i) * 64 + (e0 + j)], acc[i][j]);
}

// ---------------------------------------------------------------------------
// out[b,l,h*64+e] = sum_d Q[b,l,h,d] * KtV[b,h,d,e]
// ---------------------------------------------------------------------------
__global__ __launch_bounds__(256) void qktv_kernel(const float* __restrict__ C,
                                                   const float* __restrict__ KtV,
                                                   float* __restrict__ out)
{
  __shared__ float Qs[128][64];
  __shared__ float Ms[64][64];
  const int lt = blockIdx.x, bh = blockIdx.y;
  const int b = bh >> 3, h = bh & 7;
  const int t = threadIdx.x;
  const float* Qp = C + ((size_t)(b * 1024 + lt * 128)) * E_DIM + h * 64;
#pragma unroll
  for (int p = 0; p < 32; ++p) {
    int idx = p * 256 + t;
    Qs[idx >> 6][idx & 63] = Qp[(size_t)(idx >> 6) * E_DIM + (idx & 63)];
  }
#pragma unroll
  for (int p = 0; p < 16; ++p) {
    int idx = p * 256 + t;
    Ms[idx >> 6][idx & 63] = KtV[(size_t)bh * 4096 + idx];
  }
  __syncthreads();
  const int e0 = (t & 15) * 4;
  const int l0 = (t >> 4) * 8;
  float acc[8][4] = {};
  for (int d = 0; d < 64; ++d) {
    float4 mv = *(const float4*)&Ms[d][e0];
    float ma[4] = {mv.x, mv.y, mv.z, mv.w};
#pragma unroll
    for (int i = 0; i < 8; ++i) {
      float qv = Qs[l0 + i][d];
#pragma unroll
      for (int j = 0; j < 4; ++j) acc[i][j] = __fmaf_rn(qv, ma[j], acc[i][j]);
    }
  }
  float* op = out + ((size_t)(b * 1024 + lt * 128)) * E_DIM + h * 64;
#pragma unroll
  for (int i = 0; i < 8; ++i)
#pragma unroll
    for (int j = 0; j < 4; ++j)
      op[(size_t)(l0 + i) * E_DIM + (e0 + j)] = acc[i][j];
}

// ---------------------------------------------------------------------------
extern "C" void kernel_launch(void* const* d_in, const int* in_sizes, int n_in,
                              void* d_out, int out_size, void* d_ws, size_t ws_size,
                              hipStream_t stream) {
  const float* q   = (const float*)d_in[0];
  const float* k   = (const float*)d_in[1];
  const float* v   = (const float*)d_in[2];
  const float* wqb = (const float*)d_in[3];
  const float* wqs = (const float*)d_in[4];
  const float* wkb = (const float*)d_in[5];
  const float* wks = (const float*)d_in[6];
  const float* wvb = (const float*)d_in[7];
  const float* wvs = (const float*)d_in[8];

  char* ws = (char*)d_ws;
  const size_t WAUG_BYTES = (size_t)3 * E_DIM * KAUG * sizeof(__hip_bfloat16); // 56.6 MB
  const size_t C_BYTES    = (size_t)3 * MTOK * E_DIM * sizeof(float);          // 12.6 MB
  const size_t KTV_BYTES  = (size_t)16 * 64 * 64 * sizeof(float);              // 256 KB
  const bool full = ws_size >= WAUG_BYTES + C_BYTES + KTV_BYTES;

  float* C;
  float* KtV;
  __hip_bfloat16* waugT = (__hip_bfloat16*)ws;
  if (full) { C = (float*)(ws + WAUG_BYTES); KtV = (float*)(ws + WAUG_BYTES + C_BYTES); }
  else      { C = (float*)ws;                KtV = (float*)(ws + C_BYTES); }

  hipMemsetAsync(C, 0, C_BYTES, stream);
  hipMemsetAsync(KtV, 0, KTV_BYTES, stream);

  if (full) {
    wconv_kernel<<<dim3(KAUG / 64, E_DIM / 64, 3), 256, 0, stream>>>(
        wqs, wqb, wks, wkb, wvs, wvb, waugT);
    kan_gemm<0><<<dim3(768), 256, 0, stream>>>(
        q, k, v, waugT, wqs, wqb, wks, wkb, wvs, wvb, C);
  } else {
    kan_gemm<1><<<dim3(768), 256, 0, stream>>>(
        q, k, v, waugT, wqs, wqb, wks, wkb, wvs, wvb, C);
  }
  ktv_kernel<<<dim3(16, 16), 256, 0, stream>>>(C, KtV);
  qktv_kernel<<<dim3(8, 16), 256, 0, stream>>>(C, KtV, (float*)d_out);
}

// Round 5
// 402.173 us; speedup vs baseline: 1.0959x; 1.0959x over previous
//
#include <hip/hip_runtime.h>
#include <hip/hip_bf16.h>
#include <stdint.h>

// ---------------------------------------------------------------- geometry
#define E_DIM 512
#define GNB   35        // basis functions per input feature (G + K_DEG)
#define KSP   17920     // 512*35 spline K
#define KAUG  18432     // spline + base (512)
#define MTOK  2048      // B*L
#define BKW   64        // K window
#define NWIN  288       // KAUG/64
#define WINB  280       // first base-branch window (17920/64, exact)
#define BM    128
#define BN    128

typedef __attribute__((ext_vector_type(8))) short  short8;   // 8 bf16 MFMA A/B frag
typedef __attribute__((ext_vector_type(4))) float  floatx4;  // MFMA C/D frag

__device__ __forceinline__ short f2bf(float f) {
  __hip_bfloat16 h = __float2bfloat16(f);
  return *reinterpret_cast<short*>(&h);
}
__device__ __forceinline__ float silu_f(float x) { return x / (1.0f + __expf(-x)); }

// slice-major LDS: buf[8 slices][128 rows][16B]; slice sl holds k = kofs(sl)..+7
__device__ __forceinline__ int kofs(int sl) { return ((sl >> 2) << 5) + ((sl & 3) << 3); }

// ---------------------------------------------------------------------------
// Fused KAN GEMM, 2-deep pipelined: C[tz] = [basis(X) | silu(X)] @ W_aug.
// A,B double-buffered in LDS; B reg-staged from f32 weights (no wconv pass);
// x prefetched 2 windows ahead; 2 lgkm-only barriers per window.
// grid: 768 blocks (16 mx * 4 ny * 12 z), XCD-chunk swizzled; 256 threads.
// ---------------------------------------------------------------------------
__global__ __launch_bounds__(256, 2) void kan_gemm(
    const float* __restrict__ q, const float* __restrict__ k_in,
    const float* __restrict__ v,
    const float* __restrict__ wq_sp, const float* __restrict__ wq_base,
    const float* __restrict__ wk_sp, const float* __restrict__ wk_base,
    const float* __restrict__ wv_sp, const float* __restrict__ wv_base,
    float* __restrict__ C)
{
  __shared__ char lds[65536];   // A0 | A1 | B0 | B1, 16KB each

  // T1: bijective XCD chunking (768 = 8 * 96)
  const int bid = blockIdx.x;
  const int lid = (bid & 7) * 96 + (bid >> 3);
  const int mx = lid & 15;            // m-tile fastest: same B panel -> same XCD
  const int ny = (lid >> 4) & 3;
  const int z  = lid >> 6;            // tz*4 + ks
  const int tz = z >> 2;
  const int ks = z & 3;

  const float* X   = tz == 0 ? q : (tz == 1 ? k_in : v);
  const float* Wsp = tz == 0 ? wq_sp : (tz == 1 ? wk_sp : wv_sp);
  const float* Wb  = tz == 0 ? wq_base : (tz == 1 ? wk_base : wv_base);
  float* Cout = C + (size_t)tz * MTOK * E_DIM;

  const int m0 = mx * BM;
  const int n0 = ny * BN;
  const int t = threadIdx.x;
  const int lane = t & 63, wid = t >> 6;
  const int wm = wid >> 1, wn = wid & 1;    // 2x2 waves of 64x64
  const int fr = lane & 15, kg = lane >> 4;
  const int gB = t & 31, slB = t >> 5;      // B staging lane map

  floatx4 acc[4][4];
  const floatx4 zf = {0.f, 0.f, 0.f, 0.f};
#pragma unroll
  for (int i = 0; i < 4; ++i)
#pragma unroll
    for (int j = 0; j < 4; ++j) acc[i][j] = zf;

  const int w_lo = ks * (NWIN / 4), w_hi = w_lo + (NWIN / 4);

  float rv[32];        // staged B f32 (8 k x 4 n per thread)
  float xc[2], xn[2];  // x prefetch: current (+1) and next (+2) windows

  // -------- helpers as macros (all-static indexing)
#define WPAR(warg, k0v, elov, nev)                                  \
  const int k0v = (warg) * BKW;                                     \
  const int elov = k0v / GNB;                                       \
  int ehi_ = (k0v + BKW - 1) / GNB; if (ehi_ > 511) ehi_ = 511;     \
  const int nev = ehi_ - elov + 1;

#define ISSUE_B(warg)                                                          \
  {                                                                            \
    const int k0w = (warg) * BKW;                                              \
    const float* src = (warg) < WINB ? Wsp + (size_t)k0w * E_DIM               \
                                     : Wb + (size_t)(k0w - KSP) * E_DIM;       \
    const float* srow = src + (size_t)kofs(slB) * E_DIM + n0 + gB;             \
    _Pragma("unroll")                                                          \
    for (int j = 0; j < 8; ++j)                                                \
      _Pragma("unroll")                                                        \
      for (int i = 0; i < 4; ++i)                                              \
        rv[j * 4 + i] = srow[(size_t)j * E_DIM + 32 * i];                      \
  }

#define WRITE_B(Bb)                                                            \
  {                                                                            \
    _Pragma("unroll")                                                          \
    for (int i = 0; i < 4; ++i) {                                              \
      short8 s;                                                                \
      _Pragma("unroll")                                                        \
      for (int j = 0; j < 8; ++j) s[j] = f2bf(rv[j * 4 + i]);                  \
      *(short8*)((Bb) + slB * 2048 + (gB + 32 * i) * 16) = s;                  \
    }                                                                          \
  }

#define PREF_X(warg, xp)                                                       \
  {                                                                            \
    WPAR(warg, k0w, elow, new_)                                                \
    (void)k0w;                                                                 \
    _Pragma("unroll")                                                          \
    for (int idx = 0; idx < 2; ++idx) {                                        \
      const int p = t + idx * 256;                                             \
      if (p < 128 * new_)                                                      \
        xp[idx] = X[(size_t)(m0 + (p & 127)) * E_DIM + elow + (p >> 7)];       \
    }                                                                          \
  }

#define ZERO_A(Ab)                                                             \
  {                                                                            \
    const int4 z4 = make_int4(0, 0, 0, 0);                                     \
    _Pragma("unroll")                                                          \
    for (int p = 0; p < 4; ++p) ((int4*)(Ab))[p * 256 + t] = z4;               \
  }

#define SCATTER_A(warg, Ab, xp)                                                \
  {                                                                            \
    WPAR(warg, k0w, elow, new_)                                                \
    _Pragma("unroll")                                                          \
    for (int idx = 0; idx < 2; ++idx) {                                        \
      const int p = t + idx * 256;                                             \
      if (p < 128 * new_) {                                                    \
        const int m = p & 127, e = elow + (p >> 7);                            \
        float x = fminf(fmaxf(xp[idx], -3.0f), 3.0f - 1e-4f);                  \
        float u = (x + 3.0f) * (16.0f / 3.0f);                                 \
        int ii = (int)u; ii = ii > 31 ? 31 : ii;                               \
        float tt = u - (float)ii, omt = 1.0f - tt;                             \
        float t2 = tt * tt, t3 = t2 * tt;                                      \
        float w4[4];                                                           \
        w4[0] = omt * omt * omt * (1.0f / 6.0f);                               \
        w4[1] = (3.0f * t3 - 6.0f * t2 + 4.0f) * (1.0f / 6.0f);                \
        w4[2] = (-3.0f * t3 + 3.0f * t2 + 3.0f * tt + 1.0f) * (1.0f / 6.0f);   \
        w4[3] = t3 * (1.0f / 6.0f);                                            \
        const int kbase = e * GNB + ii - k0w;                                  \
        _Pragma("unroll")                                                      \
        for (int j = 0; j < 4; ++j) {                                          \
          const int kk = kbase + j;                                            \
          if ((unsigned)kk < BKW) {                                            \
            const int sl = ((kk >> 5) << 2) | ((kk >> 3) & 3);                 \
            *(short*)((Ab) + sl * 2048 + m * 16 + (kk & 7) * 2) = f2bf(w4[j]); \
          }                                                                    \
        }                                                                      \
      }                                                                        \
    }                                                                          \
  }

#define BASE_A(warg, Ab)                                                       \
  {                                                                            \
    const int e0w = (warg) * BKW - KSP;                                        \
    _Pragma("unroll")                                                          \
    for (int it = 0; it < 4; ++it) {                                           \
      const int c = it * 256 + t;                                              \
      const int m = c & 127, sl = c >> 7;                                      \
      const float* xs = &X[(size_t)(m0 + m) * E_DIM + e0w + kofs(sl)];         \
      floatx4 av = *(const floatx4*)xs;                                        \
      floatx4 bv = *(const floatx4*)(xs + 4);                                  \
      short8 pk;                                                               \
      pk[0] = f2bf(silu_f(av[0])); pk[1] = f2bf(silu_f(av[1]));                \
      pk[2] = f2bf(silu_f(av[2])); pk[3] = f2bf(silu_f(av[3]));                \
      pk[4] = f2bf(silu_f(bv[0])); pk[5] = f2bf(silu_f(bv[1]));                \
      pk[6] = f2bf(silu_f(bv[2])); pk[7] = f2bf(silu_f(bv[3]));                \
      *(short8*)((Ab) + sl * 2048 + m * 16) = pk;                              \
    }                                                                          \
  }

#define LGKM_BAR()                                                             \
  asm volatile("s_waitcnt lgkmcnt(0)" ::: "memory");                           \
  __builtin_amdgcn_s_barrier();

  // -------- prologue: build window w_lo, prefetch w_lo / w_lo+1
  {
    ISSUE_B(w_lo);
    PREF_X(w_lo, xc);
    PREF_X(w_lo + 1, xn);
    char* Ab = lds + (w_lo & 1) * 16384;
    char* Bb = lds + 32768 + (w_lo & 1) * 16384;
    ZERO_A(Ab);
    LGKM_BAR();                      // zeros visible
    SCATTER_A(w_lo, Ab, xc);         // w_lo always spline (<= 216)
    WRITE_B(Bb);
  }

  // -------- main loop
  for (int w = w_lo; w < w_hi; ++w) {
    LGKM_BAR();                      // top: A[w], B[w] visible to all waves

    const int wn1 = (w + 1 < w_hi) ? w + 1 : w_hi - 1;   // window params (clamped)
    const int wn2 = (w + 2 < w_hi) ? w + 2 : w_hi - 1;
    const int pn = (w + 1) & 1;                          // buffer parity (NOT clamped)
    char* Acur = lds + (w & 1) * 16384;
    char* Bcur = lds + 32768 + (w & 1) * 16384;
    char* Anxt = lds + pn * 16384;
    char* Bnxt = lds + 32768 + pn * 16384;

    ISSUE_B(wn1);                    // global->reg, used after next barrier
    xc[0] = xn[0]; xc[1] = xn[1];    // rotate x pipeline
    if (wn2 < WINB) { PREF_X(wn2, xn); }
    if (wn1 < WINB) { ZERO_A(Anxt); }

    LGKM_BAR();                      // mid: zeros of A[next] visible

    // ---- MFMA on current window (compiler inserts lgkmcnt for frag reads)
    const int arow = (wm * 64 + fr) * 16;
    const int brow = (wn * 64 + fr) * 16;
    const int sbase = kg * 2048;
#pragma unroll
    for (int kc = 0; kc < 2; ++kc) {
      const int so = sbase + kc * 8192;
      short8 af[4], bfv[4];
#pragma unroll
      for (int fm = 0; fm < 4; ++fm)
        af[fm] = *(const short8*)(Acur + so + arow + fm * 256);
#pragma unroll
      for (int fn = 0; fn < 4; ++fn)
        bfv[fn] = *(const short8*)(Bcur + so + brow + fn * 256);
#pragma unroll
      for (int fm = 0; fm < 4; ++fm)
#pragma unroll
        for (int fn = 0; fn < 4; ++fn)
          acc[fm][fn] = __builtin_amdgcn_mfma_f32_16x16x32_bf16(
              af[fm], bfv[fn], acc[fm][fn], 0, 0, 0);
    }

    // ---- build next window's A + write next B (overlaps MFMA pipe)
    if (wn1 < WINB) { SCATTER_A(wn1, Anxt, xc); }
    else            { BASE_A(wn1, Anxt); }
    WRITE_B(Bnxt);
  }

  // -------- split-K epilogue (C pre-zeroed)
  const int rowb = kg * 4;
#pragma unroll
  for (int fm = 0; fm < 4; ++fm)
#pragma unroll
    for (int fn = 0; fn < 4; ++fn)
#pragma unroll
      for (int r = 0; r < 4; ++r)
        atomicAdd(&Cout[(size_t)(m0 + wm * 64 + fm * 16 + rowb + r) * E_DIM
                        + (n0 + wn * 64 + fn * 16 + fr)],
                  acc[fm][fn][r]);
}

// ---------------------------------------------------------------------------
// KtV[b,h,d,e] = sum_s K[b,h,s,d] * V[b,h,s,e]   (f32, s-chunked + atomics)
// ---------------------------------------------------------------------------
__global__ __launch_bounds__(256) void ktv_kernel(const float* __restrict__ C,
                                                  float* __restrict__ KtV)
{
  __shared__ float Ks[64][64];
  __shared__ float Vs[64][64];
  const int sc = blockIdx.x, bh = blockIdx.y;
  const int b = bh >> 3, h = bh & 7;
  const int t = threadIdx.x;
  const size_t base = ((size_t)(b * 1024 + sc * 64)) * E_DIM + h * 64;
  const float* Kp = C + (size_t)MTOK * E_DIM + base;
  const float* Vp = C + (size_t)2 * MTOK * E_DIM + base;
#pragma unroll
  for (int p = 0; p < 16; ++p) {
    int idx = p * 256 + t;
    int r = idx >> 6, c = idx & 63;
    Ks[r][c] = Kp[(size_t)r * E_DIM + c];
    Vs[r][c] = Vp[(size_t)r * E_DIM + c];
  }
  __syncthreads();
  const int d0 = (t & 15) * 4, e0 = (t >> 4) * 4;
  float acc[4][4] = {};
  for (int s = 0; s < 64; ++s) {
    float4 kv = *(const float4*)&Ks[s][d0];
    float4 vv = *(const float4*)&Vs[s][e0];
    float ka[4] = {kv.x, kv.y, kv.z, kv.w};
    float va[4] = {vv.x, vv.y, vv.z, vv.w};
#pragma unroll
    for (int i = 0; i < 4; ++i)
#pragma unroll
      for (int j = 0; j < 4; ++j) acc[i][j] = __fmaf_rn(ka[i], va[j], acc[i][j]);
  }
  float* dst = KtV + (size_t)bh * 4096;
#pragma unroll
  for (int i = 0; i < 4; ++i)
#pragma unroll
    for (int j = 0; j < 4; ++j)
      atomicAdd(&dst[(d0 + i) * 64 + (e0 + j)], acc[i][j]);
}

// ---------------------------------------------------------------------------
// out[b,l,h*64+e] = sum_d Q[b,l,h,d] * KtV[b,h,d,e]
// ---------------------------------------------------------------------------
__global__ __launch_bounds__(256) void qktv_kernel(const float* __restrict__ C,
                                                   const float* __restrict__ KtV,
                                                   float* __restrict__ out)
{
  __shared__ float Qs[128][64];
  __shared__ float Ms[64][64];
  const int lt = blockIdx.x, bh = blockIdx.y;
  const int b = bh >> 3, h = bh & 7;
  const int t = threadIdx.x;
  const float* Qp = C + ((size_t)(b * 1024 + lt * 128)) * E_DIM + h * 64;
#pragma unroll
  for (int p = 0; p < 32; ++p) {
    int idx = p * 256 + t;
    Qs[idx >> 6][idx & 63] = Qp[(size_t)(idx >> 6) * E_DIM + (idx & 63)];
  }
#pragma unroll
  for (int p = 0; p < 16; ++p) {
    int idx = p * 256 + t;
    Ms[idx >> 6][idx & 63] = KtV[(size_t)bh * 4096 + idx];
  }
  __syncthreads();
  const int e0 = (t & 15) * 4;
  const int l0 = (t >> 4) * 8;
  float acc[8][4] = {};
  for (int d = 0; d < 64; ++d) {
    float4 mv = *(const float4*)&Ms[d][e0];
    float ma[4] = {mv.x, mv.y, mv.z, mv.w};
#pragma unroll
    for (int i = 0; i < 8; ++i) {
      float qv = Qs[l0 + i][d];
#pragma unroll
      for (int j = 0; j < 4; ++j) acc[i][j] = __fmaf_rn(qv, ma[j], acc[i][j]);
    }
  }
  float* op = out + ((size_t)(b * 1024 + lt * 128)) * E_DIM + h * 64;
#pragma unroll
  for (int i = 0; i < 8; ++i)
#pragma unroll
    for (int j = 0; j < 4; ++j)
      op[(size_t)(l0 + i) * E_DIM + (e0 + j)] = acc[i][j];
}

// ---------------------------------------------------------------------------
extern "C" void kernel_launch(void* const* d_in, const int* in_sizes, int n_in,
                              void* d_out, int out_size, void* d_ws, size_t ws_size,
                              hipStream_t stream) {
  const float* q   = (const float*)d_in[0];
  const float* k   = (const float*)d_in[1];
  const float* v   = (const float*)d_in[2];
  const float* wqb = (const float*)d_in[3];
  const float* wqs = (const float*)d_in[4];
  const float* wkb = (const float*)d_in[5];
  const float* wks = (const float*)d_in[6];
  const float* wvb = (const float*)d_in[7];
  const float* wvs = (const float*)d_in[8];

  char* ws = (char*)d_ws;
  const size_t C_BYTES   = (size_t)3 * MTOK * E_DIM * sizeof(float);   // 12.6 MB
  const size_t KTV_BYTES = (size_t)16 * 64 * 64 * sizeof(float);       // 256 KB
  float* C   = (float*)ws;
  float* KtV = (float*)(ws + C_BYTES);

  (void)hipMemsetAsync(C, 0, C_BYTES, stream);
  (void)hipMemsetAsync(KtV, 0, KTV_BYTES, stream);

  kan_gemm<<<dim3(768), 256, 0, stream>>>(
      q, k, v, wqs, wqb, wks, wkb, wvs, wvb, C);
  ktv_kernel<<<dim3(16, 16), 256, 0, stream>>>(C, KtV);
  qktv_kernel<<<dim3(8, 16), 256, 0, stream>>>(C, KtV, (float*)d_out);
}